// Round 1
// baseline (82.260 us; speedup 1.0000x reference)
//
#include <hip/hip_runtime.h>
#include <math.h>

#define NF 16
#define B_ELEMS 4194304

// 1/(2*pi)
#define INV_2PI 0.15915494309189535f

// ws layout (floats): [0:16) f2 = freq/(2pi), [16:32) p2 = phi/(2pi),
//                     [32:48) Rs = R/frange,  [48] off_scaled = offset/frange
__global__ void fourier_setup_kernel(const float* __restrict__ freqs,
                                     const float* __restrict__ offp,
                                     const float* __restrict__ sc,
                                     const float* __restrict__ cc,
                                     float* __restrict__ ws) {
    int lane = threadIdx.x;  // single wave of 64
    float s = 0.f, c = 0.f, fq = 0.f;
    if (lane < NF) { s = sc[lane]; c = cc[lane]; fq = freqs[lane]; }
    float absum = fabsf(s) + fabsf(c);
    // butterfly reduce across the full 64-lane wave (lanes >= NF contribute 0)
    #pragma unroll
    for (int off = 1; off < 64; off <<= 1)
        absum += __shfl_xor(absum, off, 64);
    float frange = fmaxf(1.0f, absum + 1e-8f);
    float inv = 1.0f / frange;
    if (lane < NF) {
        float R   = sqrtf(s * s + c * c);
        float phi = atan2f(c, s);
        ws[lane]          = fq * INV_2PI;
        ws[NF + lane]     = phi * INV_2PI;
        ws[2 * NF + lane] = R * inv;
    }
    if (lane == 0) ws[3 * NF] = offp[0] * inv;
}

__global__ __launch_bounds__(256) void fourier_main_kernel(
        const float* __restrict__ t,
        const float* __restrict__ ws,
        float* __restrict__ out,
        int n4) {
    // Wave-uniform coefficient loads (compiler should scalarize to s_load;
    // worst case they are L1 broadcast hits).
    float f2[NF], p2[NF], Rs[NF];
    #pragma unroll
    for (int k = 0; k < NF; ++k) {
        f2[k] = ws[k];
        p2[k] = ws[NF + k];
        Rs[k] = ws[2 * NF + k];
    }
    float off = ws[3 * NF];

    int idx    = blockIdx.x * blockDim.x + threadIdx.x;
    int stride = gridDim.x * blockDim.x;
    const float4* __restrict__ t4 = (const float4*)t;
    float4* __restrict__ o4       = (float4*)out;

    for (int i = idx; i < n4; i += stride) {
        float4 tv = t4[i];
        float tt[4] = {tv.x, tv.y, tv.z, tv.w};
        float acc[4];
        #pragma unroll
        for (int j = 0; j < 4; ++j) acc[j] = off;
        #pragma unroll
        for (int k = 0; k < NF; ++k) {
            #pragma unroll
            for (int j = 0; j < 4; ++j) {
                // r in revolutions; |r| <~ 1.5 so raw v_sin_f32 is accurate
                float r = fmaf(tt[j], f2[k], p2[k]);
                acc[j] = fmaf(Rs[k], __builtin_amdgcn_sinf(r), acc[j]);
            }
        }
        float4 ov;
        ov.x = acc[0]; ov.y = acc[1]; ov.z = acc[2]; ov.w = acc[3];
        o4[i] = ov;
    }
}

extern "C" void kernel_launch(void* const* d_in, const int* in_sizes, int n_in,
                              void* d_out, int out_size, void* d_ws, size_t ws_size,
                              hipStream_t stream) {
    const float* t     = (const float*)d_in[0];
    const float* freqs = (const float*)d_in[1];
    const float* offp  = (const float*)d_in[2];
    const float* sc    = (const float*)d_in[3];
    const float* cc    = (const float*)d_in[4];
    float* out = (float*)d_out;
    float* ws  = (float*)d_ws;

    // Setup runs every launch: ws is re-poisoned before each timed call.
    fourier_setup_kernel<<<1, 64, 0, stream>>>(freqs, offp, sc, cc, ws);

    int n4 = out_size / 4;  // 1048576 float4 groups
    int block = 256;
    int grid  = 2048;       // 8 blocks/CU; 2 float4 iterations per thread
    fourier_main_kernel<<<grid, block, 0, stream>>>(t, ws, out, n4);
}